// Round 3
// baseline (121202.075 us; speedup 1.0000x reference)
//
#include <hip/hip_runtime.h>

#define GROUPS 8
#define GR 32
#define THREADS 512
#define TSLEN 512
#define ID 64
#define N0 306
#define N1 204
#define N2 2
#define D0 370
#define D1 510
#define D2 206
#define SSTR 521   // odd stride -> conflict-free LDS columns

// ws float offsets (exactly round-1-proven footprint: 1,134,880 floats)
#define OFF_W40 0
#define OFF_W41 452880
#define OFF_W42 869040
#define OFF_B40 870688
#define OFF_B41 871912
#define OFF_B42 872728
#define OFF_HI  872736    // [2][256][306]
#define OFF_HC  1029408   // [2][256][204]
#define OFF_HM  1133856   // [2][256][2]

__device__ __forceinline__ float cellact(float a0, float a1, float a2, float a3, float4 b) {
  float f1 = tanhf(a0 + b.x);
  float f2 = tanhf(a1 + b.y);
  float tv = 1.f / (1.f + __expf((a2 + b.z) - (a3 + b.w)));  // sigmoid(tb - ta)
  return f1 * (1.f - tv) + tv * f2;
}

__global__ __launch_bounds__(256) void prep_kernel(
    const float* __restrict__ h0,
    const float* __restrict__ f1w0, const float* __restrict__ f2w0,
    const float* __restrict__ taw0, const float* __restrict__ tbw0, const int* __restrict__ m0,
    const float* __restrict__ f1b0, const float* __restrict__ f2b0,
    const float* __restrict__ tab0, const float* __restrict__ tbb0,
    const float* __restrict__ f1w1, const float* __restrict__ f2w1,
    const float* __restrict__ taw1, const float* __restrict__ tbw1, const int* __restrict__ m1,
    const float* __restrict__ f1b1, const float* __restrict__ f2b1,
    const float* __restrict__ tab1, const float* __restrict__ tbb1,
    const float* __restrict__ f1w2, const float* __restrict__ f2w2,
    const float* __restrict__ taw2, const float* __restrict__ tbw2, const int* __restrict__ m2,
    const float* __restrict__ f1b2, const float* __restrict__ f2b2,
    const float* __restrict__ tab2, const float* __restrict__ tbb2,
    float* __restrict__ ws, float* __restrict__ out)
{
  const int A0 = N0*D0, A1 = N1*D1, A2 = N2*D2;
  int j = blockIdx.x*256 + threadIdx.x;
  if (j < A0) {
    float mm = (float)m0[j];
    ((float4*)(ws+OFF_W40))[j] = make_float4(f1w0[j]*mm, f2w0[j]*mm, taw0[j], tbw0[j]);
    return;
  }
  j -= A0;
  if (j < A1) {
    float mm = (float)m1[j];
    ((float4*)(ws+OFF_W41))[j] = make_float4(f1w1[j]*mm, f2w1[j]*mm, taw1[j], tbw1[j]);
    return;
  }
  j -= A1;
  if (j < A2) {
    float mm = (float)m2[j];
    ((float4*)(ws+OFF_W42))[j] = make_float4(f1w2[j]*mm, f2w2[j]*mm, taw2[j], tbw2[j]);
    return;
  }
  j -= A2;
  if (j < N0) { ((float4*)(ws+OFF_B40))[j] = make_float4(f1b0[j], f2b0[j], tab0[j], tbb0[j]); return; }
  j -= N0;
  if (j < N1) { ((float4*)(ws+OFF_B41))[j] = make_float4(f1b1[j], f2b1[j], tab1[j], tbb1[j]); return; }
  j -= N1;
  if (j < N2) { ((float4*)(ws+OFF_B42))[j] = make_float4(f1b2[j], f2b2[j], tab2[j], tbb2[j]); return; }
  j -= N2;
  // state init into buf=1: base index (256 + rglob)
  if (j < 256*N0) { int r = j/N0, c = j - r*N0; (ws+OFF_HI)[(256 + r)*N0 + c] = h0[r*512 + c]; return; }
  j -= 256*N0;
  if (j < 256*N1) { int r = j/N1, c = j - r*N1; (ws+OFF_HC)[(256 + r)*N1 + c] = h0[r*512 + N0 + c]; return; }
  j -= 256*N1;
  if (j < 256*N2) { int r = j/N2, c = j - r*N2; (ws+OFF_HM)[(256 + r)*N2 + c] = h0[r*512 + N0 + N1 + c]; return; }
  j -= 256*N2;
  // sync counters live in out's PREDICTIONS region (ints 0..511). Group-local:
  // cA[g] = int g*64, cB[g] = int g*64+32 -> only group g's own epilogue overwrites them.
  if (j < 512) { ((int*)out)[j] = 0; return; }
}

__global__ __launch_bounds__(THREADS, 1) void lnn_main(
    const float* __restrict__ x,
    const float* __restrict__ fcw, const float* __restrict__ fcb,
    const float* __restrict__ W40, const float* __restrict__ B40,
    const float* __restrict__ W41, const float* __restrict__ B41,
    const float* __restrict__ W42, const float* __restrict__ B42,
    float* __restrict__ hig, float* __restrict__ hcg, float* __restrict__ hmg,
    int* __restrict__ ctr, float* __restrict__ out)
{
  extern __shared__ float slab[];   // [32][SSTR]
  const int tid = threadIdx.x;
  const int bid = blockIdx.x;
  const int g = bid >> 5;           // group 0..7 (32 rows each)
  const int s = bid & 31;           // unit-slice 0..31 (bid%8==s%8 -> same-s on same XCD)
  const int r0 = g * GR;

  const int nu0 = (s < 18) ? 10 : 9;
  const int u00 = s * 9 + (s < 18 ? s : 18);
  const int nu1 = (s < 12) ? 7 : 6;
  const int u01 = s * 6 + (s < 12 ? s : 12);

  int* cA = ctr + g * 64;       // inside group g's own predictions region
  int* cB = ctr + g * 64 + 32;

  for (int t = 0; t < TSLEN; ++t) {
    const int cur = t & 1, prv = cur ^ 1;

    // ---------- stage slab A: [x_t | hi(t-1)]  (32 x 370) ----------
    for (int i = tid; i < GR * D0; i += THREADS) {
      int r = i / D0, c = i - r * D0;
      float v = (c < ID) ? x[((size_t)(r0 + r) * TSLEN + t) * ID + c]
                         : hig[(prv * 256 + r0 + r) * N0 + (c - ID)];
      slab[r * SSTR + c] = v;
    }
    __syncthreads();

    // ---------- compute hi(t) ----------
    if (tid < 256) {                     // units 0..7 full dots (waves 0-3)
      int u = u00 + (tid >> 5), r = tid & 31;
      const float4* wr = (const float4*)W40 + (size_t)u * D0;
      const float* xr = slab + r * SSTR;
      float a0 = 0.f, a1 = 0.f, a2 = 0.f, a3 = 0.f;
      #pragma unroll 4
      for (int d = 0; d < D0; ++d) {
        float4 w = wr[d]; float xv = xr[d];
        a0 = fmaf(w.x, xv, a0); a1 = fmaf(w.y, xv, a1);
        a2 = fmaf(w.z, xv, a2); a3 = fmaf(w.w, xv, a3);
      }
      float4 b = ((const float4*)B40)[u];
      hig[(cur * 256 + r0 + r) * N0 + u] = cellact(a0, a1, a2, a3, b);
    } else {                             // units 8..9 split-K x4 (waves 4-7)
      int q = tid - 256;
      int uu = 8 + (q >> 7);
      if (uu < nu0) {
        int r = (q >> 2) & 31, k = q & 3;
        int d0 = k * 93, d1 = (k == 3) ? D0 : d0 + 93;
        int u = u00 + uu;
        const float4* wr = (const float4*)W40 + (size_t)u * D0;
        const float* xr = slab + r * SSTR;
        float a0 = 0.f, a1 = 0.f, a2 = 0.f, a3 = 0.f;
        #pragma unroll 2
        for (int d = d0; d < d1; ++d) {
          float4 w = wr[d]; float xv = xr[d];
          a0 = fmaf(w.x, xv, a0); a1 = fmaf(w.y, xv, a1);
          a2 = fmaf(w.z, xv, a2); a3 = fmaf(w.w, xv, a3);
        }
        a0 += __shfl_xor(a0, 1); a1 += __shfl_xor(a1, 1); a2 += __shfl_xor(a2, 1); a3 += __shfl_xor(a3, 1);
        a0 += __shfl_xor(a0, 2); a1 += __shfl_xor(a1, 2); a2 += __shfl_xor(a2, 2); a3 += __shfl_xor(a3, 2);
        if (k == 0) {
          float4 b = ((const float4*)B40)[u];
          hig[(cur * 256 + r0 + r) * N0 + u] = cellact(a0, a1, a2, a3, b);
        }
      }
    }

    // ---------- group sync A ----------
    __threadfence();
    __syncthreads();
    if (tid == 0) {
      __hip_atomic_fetch_add(cA, 1, __ATOMIC_RELEASE, __HIP_MEMORY_SCOPE_AGENT);
      for (int spin = 0; spin < 200000; ++spin) {
        if (__hip_atomic_load(cA, __ATOMIC_ACQUIRE, __HIP_MEMORY_SCOPE_AGENT) >= 32 * (t + 1)) break;
        __builtin_amdgcn_s_sleep(2);
      }
    }
    __syncthreads();
    __threadfence();

    // ---------- stage slab B: [hi(t) | hc(t-1)]  (32 x 510) ----------
    for (int i = tid; i < GR * D1; i += THREADS) {
      int r = i / D1, c = i - r * D1;
      float v = (c < N0) ? hig[(cur * 256 + r0 + r) * N0 + c]
                         : hcg[(prv * 256 + r0 + r) * N1 + (c - N0)];
      slab[r * SSTR + c] = v;
    }
    __syncthreads();

    // ---------- compute hc(t) (+ hm(t-1) on wave 7) ----------
    if (tid < 192) {                     // units 0..5 full dots (waves 0-2)
      int u = u01 + (tid >> 5), r = tid & 31;
      const float4* wr = (const float4*)W41 + (size_t)u * D1;
      const float* xr = slab + r * SSTR;
      float a0 = 0.f, a1 = 0.f, a2 = 0.f, a3 = 0.f;
      #pragma unroll 4
      for (int d = 0; d < D1; ++d) {
        float4 w = wr[d]; float xv = xr[d];
        a0 = fmaf(w.x, xv, a0); a1 = fmaf(w.y, xv, a1);
        a2 = fmaf(w.z, xv, a2); a3 = fmaf(w.w, xv, a3);
      }
      float4 b = ((const float4*)B41)[u];
      hcg[(cur * 256 + r0 + r) * N1 + u] = cellact(a0, a1, a2, a3, b);
    } else if (tid < 256) {              // unit 6 (7th) split-K x2 on wave 3
      if (nu1 == 7) {
        int l = tid - 192;
        int r = l >> 1, k = l & 1;
        int u = u01 + 6;
        int d0 = k * 255, d1 = d0 + 255;
        const float4* wr = (const float4*)W41 + (size_t)u * D1;
        const float* xr = slab + r * SSTR;
        float a0 = 0.f, a1 = 0.f, a2 = 0.f, a3 = 0.f;
        #pragma unroll 2
        for (int d = d0; d < d1; ++d) {
          float4 w = wr[d]; float xv = xr[d];
          a0 = fmaf(w.x, xv, a0); a1 = fmaf(w.y, xv, a1);
          a2 = fmaf(w.z, xv, a2); a3 = fmaf(w.w, xv, a3);
        }
        a0 += __shfl_xor(a0, 1); a1 += __shfl_xor(a1, 1); a2 += __shfl_xor(a2, 1); a3 += __shfl_xor(a3, 1);
        if (k == 0) {
          float4 b = ((const float4*)B41)[u];
          hcg[(cur * 256 + r0 + r) * N1 + u] = cellact(a0, a1, a2, a3, b);
        }
      }
    } else if (tid >= 448 && t >= 1) {   // wave 7: hm(t-1) = cell2([hc(t-1), hm(t-2)])
      int l = tid - 448;
      int u = l >> 5, r = l & 31;
      const float4* wr = (const float4*)W42 + (size_t)u * D2;
      const float* xr = slab + r * SSTR + N0;              // hc(t-1) at cols 306..509
      const float* hmr = hmg + (cur * 256 + r0 + r) * N2;  // hm(t-2) in buf (t-2)&1 == cur
      float a0 = 0.f, a1 = 0.f, a2 = 0.f, a3 = 0.f;
      #pragma unroll 2
      for (int d = 0; d < D2; ++d) {
        float xv = (d < N1) ? xr[d] : hmr[d - N1];
        float4 w = wr[d];
        a0 = fmaf(w.x, xv, a0); a1 = fmaf(w.y, xv, a1);
        a2 = fmaf(w.z, xv, a2); a3 = fmaf(w.w, xv, a3);
      }
      float4 b = ((const float4*)B42)[u];
      hmg[(prv * 256 + r0 + r) * N2 + u] = cellact(a0, a1, a2, a3, b);  // hm(t-1) -> buf (t-1)&1
    }

    // ---------- group sync B ----------
    __threadfence();
    __syncthreads();
    if (tid == 0) {
      __hip_atomic_fetch_add(cB, 1, __ATOMIC_RELEASE, __HIP_MEMORY_SCOPE_AGENT);
      for (int spin = 0; spin < 200000; ++spin) {
        if (__hip_atomic_load(cB, __ATOMIC_ACQUIRE, __HIP_MEMORY_SCOPE_AGENT) >= 32 * (t + 1)) break;
        __builtin_amdgcn_s_sleep(2);
      }
    }
    __syncthreads();
    __threadfence();
  }

  // ---------- epilogue: slice 31 of each group computes hm(511), preds, and writes out ----------
  if (s == 31) {
    for (int i = tid; i < GR * N1; i += THREADS) {
      int r = i / N1, c = i - r * N1;
      slab[r * SSTR + N0 + c] = hcg[(256 + r0 + r) * N1 + c];
    }
    __syncthreads();
    if (tid >= 448) {   // wave 7: hm(511) = cell2([hc(511), hm(510)]); hm(510) in buf 0
      int l = tid - 448;
      int u = l >> 5, r = l & 31;
      const float4* wr = (const float4*)W42 + (size_t)u * D2;
      const float* xr = slab + r * SSTR + N0;
      const float* hmr = hmg + (0 * 256 + r0 + r) * N2;
      float a0 = 0.f, a1 = 0.f, a2 = 0.f, a3 = 0.f;
      for (int d = 0; d < D2; ++d) {
        float xv = (d < N1) ? xr[d] : hmr[d - N1];
        float4 w = wr[d];
        a0 = fmaf(w.x, xv, a0); a1 = fmaf(w.y, xv, a1);
        a2 = fmaf(w.z, xv, a2); a3 = fmaf(w.w, xv, a3);
      }
      float4 b = ((const float4*)B42)[u];
      hmg[(256 + r0 + r) * N2 + u] = cellact(a0, a1, a2, a3, b);
    }
    __syncthreads();
    if (tid < 64) {     // predictions = hm(511) @ fcw^T + fcb (overwrites this group's counters; done using them)
      int r = tid >> 1, o = tid & 1;
      float h0v = hmg[(256 + r0 + r) * N2 + 0];
      float h1v = hmg[(256 + r0 + r) * N2 + 1];
      out[(size_t)(r0 + r) * 2 + o] = h0v * fcw[o * 2 + 0] + h1v * fcw[o * 2 + 1] + fcb[o];
    }
    // h concat = [hi(511) | hc(511) | hm(511)] for this group's 32 rows
    for (int i = tid; i < GR * 512; i += THREADS) {
      int r = i >> 9, c = i & 511;
      float v;
      if (c < N0)            v = hig[(256 + r0 + r) * N0 + c];
      else if (c < N0 + N1)  v = hcg[(256 + r0 + r) * N1 + (c - N0)];
      else                   v = hmg[(256 + r0 + r) * N2 + (c - N0 - N1)];
      out[512 + (size_t)(r0 + r) * 512 + c] = v;
    }
  }
}

extern "C" void kernel_launch(void* const* d_in, const int* in_sizes, int n_in,
                              void* d_out, int out_size, void* d_ws, size_t ws_size,
                              hipStream_t stream) {
  const float* x    = (const float*)d_in[0];
  const float* h0   = (const float*)d_in[1];
  const float* f1w0 = (const float*)d_in[2];
  const float* f1b0 = (const float*)d_in[3];
  const float* f2w0 = (const float*)d_in[4];
  const float* f2b0 = (const float*)d_in[5];
  const float* taw0 = (const float*)d_in[6];
  const float* tab0 = (const float*)d_in[7];
  const float* tbw0 = (const float*)d_in[8];
  const float* tbb0 = (const float*)d_in[9];
  const int*   m0   = (const int*)d_in[10];
  const float* f1w1 = (const float*)d_in[11];
  const float* f1b1 = (const float*)d_in[12];
  const float* f2w1 = (const float*)d_in[13];
  const float* f2b1 = (const float*)d_in[14];
  const float* taw1 = (const float*)d_in[15];
  const float* tab1 = (const float*)d_in[16];
  const float* tbw1 = (const float*)d_in[17];
  const float* tbb1 = (const float*)d_in[18];
  const int*   m1   = (const int*)d_in[19];
  const float* f1w2 = (const float*)d_in[20];
  const float* f1b2 = (const float*)d_in[21];
  const float* f2w2 = (const float*)d_in[22];
  const float* f2b2 = (const float*)d_in[23];
  const float* taw2 = (const float*)d_in[24];
  const float* tab2 = (const float*)d_in[25];
  const float* tbw2 = (const float*)d_in[26];
  const float* tbb2 = (const float*)d_in[27];
  const int*   m2   = (const int*)d_in[28];
  const float* fcw  = (const float*)d_in[29];
  const float* fcb  = (const float*)d_in[30];

  float* ws  = (float*)d_ws;
  float* out = (float*)d_out;

  prep_kernel<<<1367, 256, 0, stream>>>(
      h0,
      f1w0, f2w0, taw0, tbw0, m0, f1b0, f2b0, tab0, tbb0,
      f1w1, f2w1, taw1, tbw1, m1, f1b1, f2b1, tab1, tbb1,
      f1w2, f2w2, taw2, tbw2, m2, f1b2, f2b2, tab2, tbb2,
      ws, out);

  static const int kShmem = 84000;  // > 160KiB/2 -> 1 WG/CU -> 256 WGs co-resident on 256 CUs
  hipFuncSetAttribute((const void*)lnn_main, hipFuncAttributeMaxDynamicSharedMemorySize, kShmem);
  lnn_main<<<256, THREADS, kShmem, stream>>>(
      x, fcw, fcb,
      ws + OFF_W40, ws + OFF_B40,
      ws + OFF_W41, ws + OFF_B41,
      ws + OFF_W42, ws + OFF_B42,
      ws + OFF_HI, ws + OFF_HC, ws + OFF_HM,
      (int*)out, out);
}

// Round 4
// 54290.906 us; speedup vs baseline: 2.2325x; 2.2325x over previous
//
#include <hip/hip_runtime.h>

#define TSLEN 512
#define ID 64
#define N0 306
#define N1 204
#define N2 2
#define D0 370
#define D1 510
#define D2 206
#define D0P 384
#define D1P 512
#define D2P 256

// ws float offsets (total 669,440 floats = 2.68 MB)
#define OFF_WFFA 0         // [306][384] float2
#define OFF_WTDA 235008    // [306][384] float
#define OFF_WFFB 352512    // [204][512] float2
#define OFF_WTDB 561408    // [204][512] float
#define OFF_WFFC 665856    // [2][256] float2
#define OFF_WTDC 666880    // [2][256] float
#define OFF_BA   667392    // [306] float4 (b1, b2, btd, 0)
#define OFF_BB   668616    // [204] float4
#define OFF_BC   669432    // [2] float4

__global__ __launch_bounds__(256) void prep_kernel(
    const float* __restrict__ f1w0, const float* __restrict__ f2w0,
    const float* __restrict__ taw0, const float* __restrict__ tbw0, const int* __restrict__ m0,
    const float* __restrict__ f1b0, const float* __restrict__ f2b0,
    const float* __restrict__ tab0, const float* __restrict__ tbb0,
    const float* __restrict__ f1w1, const float* __restrict__ f2w1,
    const float* __restrict__ taw1, const float* __restrict__ tbw1, const int* __restrict__ m1,
    const float* __restrict__ f1b1, const float* __restrict__ f2b1,
    const float* __restrict__ tab1, const float* __restrict__ tbb1,
    const float* __restrict__ f1w2, const float* __restrict__ f2w2,
    const float* __restrict__ taw2, const float* __restrict__ tbw2, const int* __restrict__ m2,
    const float* __restrict__ f1b2, const float* __restrict__ f2b2,
    const float* __restrict__ tab2, const float* __restrict__ tbb2,
    float* __restrict__ ws)
{
  int j = blockIdx.x * 256 + threadIdx.x;
  if (j < 306 * D0P) {
    int u = j / D0P, d = j - u * D0P;
    float f1 = 0.f, f2 = 0.f, td = 0.f;
    if (d < D0) {
      int idx = u * D0 + d;
      float m = (float)m0[idx];
      f1 = f1w0[idx] * m; f2 = f2w0[idx] * m; td = tbw0[idx] - taw0[idx];
    }
    ws[OFF_WFFA + 2 * j] = f1; ws[OFF_WFFA + 2 * j + 1] = f2; ws[OFF_WTDA + j] = td;
    return;
  }
  j -= 306 * D0P;
  if (j < 204 * D1P) {
    int u = j / D1P, d = j - u * D1P;
    float f1 = 0.f, f2 = 0.f, td = 0.f;
    if (d < D1) {
      int idx = u * D1 + d;
      float m = (float)m1[idx];
      f1 = f1w1[idx] * m; f2 = f2w1[idx] * m; td = tbw1[idx] - taw1[idx];
    }
    ws[OFF_WFFB + 2 * j] = f1; ws[OFF_WFFB + 2 * j + 1] = f2; ws[OFF_WTDB + j] = td;
    return;
  }
  j -= 204 * D1P;
  if (j < 2 * D2P) {
    int u = j / D2P, d = j - u * D2P;
    float f1 = 0.f, f2 = 0.f, td = 0.f;
    if (d < D2) {
      int idx = u * D2 + d;
      float m = (float)m2[idx];
      f1 = f1w2[idx] * m; f2 = f2w2[idx] * m; td = tbw2[idx] - taw2[idx];
    }
    ws[OFF_WFFC + 2 * j] = f1; ws[OFF_WFFC + 2 * j + 1] = f2; ws[OFF_WTDC + j] = td;
    return;
  }
  j -= 2 * D2P;
  if (j < 306) { ((float4*)(ws + OFF_BA))[j] = make_float4(f1b0[j], f2b0[j], tbb0[j] - tab0[j], 0.f); return; }
  j -= 306;
  if (j < 204) { ((float4*)(ws + OFF_BB))[j] = make_float4(f1b1[j], f2b1[j], tbb1[j] - tab1[j], 0.f); return; }
  j -= 204;
  if (j < 2)   { ((float4*)(ws + OFF_BC))[j] = make_float4(f1b2[j], f2b2[j], tbb2[j] - tab2[j], 0.f); return; }
}

__device__ __forceinline__ float cellact3(float f1, float f2, float td, float4 b) {
  float t1 = tanhf(f1 + b.x);
  float t2 = tanhf(f2 + b.y);
  float tv = 1.f / (1.f + __expf(-(td + b.z)));
  return t1 * (1.f - tv) + tv * t2;
}

// One block = 2 batch rows, full recurrence, zero inter-block communication.
__global__ __launch_bounds__(512) void lnn_main(
    const float* __restrict__ x, const float* __restrict__ h0,
    const float* __restrict__ fcw, const float* __restrict__ fcb,
    const float* __restrict__ WffA, const float* __restrict__ WtdA, const float* __restrict__ BA,
    const float* __restrict__ WffB, const float* __restrict__ WtdB, const float* __restrict__ BB,
    const float* __restrict__ WffC, const float* __restrict__ WtdC, const float* __restrict__ BC,
    float* __restrict__ out)
{
  __shared__ float sA[2][D0P];   // [x_t(64) | hi(306) | pad]
  __shared__ float sB[2][D1P];   // [hi_new(306) | hc(204) | pad]
  __shared__ float sC[2][D2P];   // [hc_new(204) | hm(2) | pad]

  const int tid  = threadIdx.x;
  const int wave = tid >> 6;
  const int lane = tid & 63;
  const int k  = lane & 15;         // k-chunk 0..15
  const int r  = (lane >> 4) & 1;   // row within block
  const int uo = lane >> 5;         // unit parity within pass
  const int r0g = blockIdx.x * 2;

  const float4* BA4 = (const float4*)BA;
  const float4* BB4 = (const float4*)BB;
  const float4* BC4 = (const float4*)BC;

  // ---- init LDS state from h0 ----
  for (int i = tid; i < 2 * D0P; i += 512) {
    int rr = i / D0P, c = i - rr * D0P;
    sA[rr][c] = (c >= ID && c < ID + N0) ? h0[(size_t)(r0g + rr) * 512 + (c - ID)] : 0.f;
  }
  for (int i = tid; i < 2 * D1P; i += 512) {
    int rr = i / D1P, c = i - rr * D1P;
    sB[rr][c] = (c >= N0 && c < N0 + N1) ? h0[(size_t)(r0g + rr) * 512 + c] : 0.f;
  }
  for (int i = tid; i < 2 * D2P; i += 512) {
    int rr = i / D2P, c = i - rr * D2P;
    sC[rr][c] = (c >= N1 && c < N1 + N2) ? h0[(size_t)(r0g + rr) * 512 + (510 - N1) + c] : 0.f;
  }
  __syncthreads();

  for (int t = 0; t < TSLEN; ++t) {
    // ---- stage x_t ----
    if (tid < 128) {
      int rr = tid >> 6, c = tid & 63;
      sA[rr][c] = x[((size_t)(r0g + rr) * TSLEN + t) * ID + c];
    }
    __syncthreads();  // B1

    // ---- reg-load A slices (24 floats per lane) ----
    float4 xa[6];
    {
      const float4* p = (const float4*)&sA[r][k * 24];
      #pragma unroll
      for (int j = 0; j < 6; ++j) xa[j] = p[j];
    }
    __syncthreads();  // B2: protects sA writes below

    // ---- phase A: hi(t), 153 passes of 2 units ----
    for (int p5 = wave; p5 < 153; p5 += 8) {
      int u = 2 * p5 + uo;
      const float4* pf = (const float4*)(WffA + (size_t)u * (2 * D0P) + k * 48);
      const float4* pt = (const float4*)(WtdA + (size_t)u * D0P + k * 24);
      float f1 = 0.f, f2 = 0.f, td = 0.f;
      #pragma unroll
      for (int j4 = 0; j4 < 6; ++j4) {
        float4 xv = xa[j4];
        float4 wa = pf[2 * j4], wb = pf[2 * j4 + 1], wt = pt[j4];
        f1 = fmaf(wa.x, xv.x, f1); f2 = fmaf(wa.y, xv.x, f2); td = fmaf(wt.x, xv.x, td);
        f1 = fmaf(wa.z, xv.y, f1); f2 = fmaf(wa.w, xv.y, f2); td = fmaf(wt.y, xv.y, td);
        f1 = fmaf(wb.x, xv.z, f1); f2 = fmaf(wb.y, xv.z, f2); td = fmaf(wt.z, xv.z, td);
        f1 = fmaf(wb.z, xv.w, f1); f2 = fmaf(wb.w, xv.w, f2); td = fmaf(wt.w, xv.w, td);
      }
      #pragma unroll
      for (int m = 1; m <= 8; m <<= 1) {
        f1 += __shfl_xor(f1, m); f2 += __shfl_xor(f2, m); td += __shfl_xor(td, m);
      }
      if (k == 0) {
        float act = cellact3(f1, f2, td, BA4[u]);
        sB[r][u] = act;
        sA[r][ID + u] = act;   // hi for next step
      }
    }
    __syncthreads();  // B3

    // ---- reg-load B slices (32 floats per lane) ----
    float4 xb[8];
    {
      const float4* p = (const float4*)&sB[r][k * 32];
      #pragma unroll
      for (int j = 0; j < 8; ++j) xb[j] = p[j];
    }
    __syncthreads();  // B4: protects sB writes below

    // ---- phase B: hc(t), 102 passes of 2 units ----
    for (int p5 = wave; p5 < 102; p5 += 8) {
      int u = 2 * p5 + uo;
      const float4* pf = (const float4*)(WffB + (size_t)u * (2 * D1P) + k * 64);
      const float4* pt = (const float4*)(WtdB + (size_t)u * D1P + k * 32);
      float f1 = 0.f, f2 = 0.f, td = 0.f;
      #pragma unroll
      for (int j4 = 0; j4 < 8; ++j4) {
        float4 xv = xb[j4];
        float4 wa = pf[2 * j4], wb = pf[2 * j4 + 1], wt = pt[j4];
        f1 = fmaf(wa.x, xv.x, f1); f2 = fmaf(wa.y, xv.x, f2); td = fmaf(wt.x, xv.x, td);
        f1 = fmaf(wa.z, xv.y, f1); f2 = fmaf(wa.w, xv.y, f2); td = fmaf(wt.y, xv.y, td);
        f1 = fmaf(wb.x, xv.z, f1); f2 = fmaf(wb.y, xv.z, f2); td = fmaf(wt.z, xv.z, td);
        f1 = fmaf(wb.z, xv.w, f1); f2 = fmaf(wb.w, xv.w, f2); td = fmaf(wt.w, xv.w, td);
      }
      #pragma unroll
      for (int m = 1; m <= 8; m <<= 1) {
        f1 += __shfl_xor(f1, m); f2 += __shfl_xor(f2, m); td += __shfl_xor(td, m);
      }
      if (k == 0) {
        float act = cellact3(f1, f2, td, BB4[u]);
        sC[r][u] = act;
        sB[r][N0 + u] = act;   // hc for next step
      }
    }
    __syncthreads();  // B5

    // ---- phase C: hm(t), wave 0 only (2 units x 2 rows) ----
    if (wave == 0) {
      float4 xc[4];
      const float4* p = (const float4*)&sC[r][k * 16];
      #pragma unroll
      for (int j = 0; j < 4; ++j) xc[j] = p[j];   // in-wave: reads precede writes below
      int u = uo;
      const float4* pf = (const float4*)(WffC + (size_t)u * (2 * D2P) + k * 32);
      const float4* pt = (const float4*)(WtdC + (size_t)u * D2P + k * 16);
      float f1 = 0.f, f2 = 0.f, td = 0.f;
      #pragma unroll
      for (int j4 = 0; j4 < 4; ++j4) {
        float4 xv = xc[j4];
        float4 wa = pf[2 * j4], wb = pf[2 * j4 + 1], wt = pt[j4];
        f1 = fmaf(wa.x, xv.x, f1); f2 = fmaf(wa.y, xv.x, f2); td = fmaf(wt.x, xv.x, td);
        f1 = fmaf(wa.z, xv.y, f1); f2 = fmaf(wa.w, xv.y, f2); td = fmaf(wt.y, xv.y, td);
        f1 = fmaf(wb.x, xv.z, f1); f2 = fmaf(wb.y, xv.z, f2); td = fmaf(wt.z, xv.z, td);
        f1 = fmaf(wb.z, xv.w, f1); f2 = fmaf(wb.w, xv.w, f2); td = fmaf(wt.w, xv.w, td);
      }
      #pragma unroll
      for (int m = 1; m <= 8; m <<= 1) {
        f1 += __shfl_xor(f1, m); f2 += __shfl_xor(f2, m); td += __shfl_xor(td, m);
      }
      if (k == 0) {
        float act = cellact3(f1, f2, td, BC4[u]);
        sC[r][N1 + u] = act;   // hm for next step / output
      }
    }
    // no barrier needed here: next writer of sC is next step's phase B (after B4)
  }

  __syncthreads();  // make wave 0's final hm visible

  // ---- epilogue ----
  if (tid < 4) {
    int rr = tid >> 1, o = tid & 1;
    float h0v = sC[rr][N1 + 0], h1v = sC[rr][N1 + 1];
    out[(size_t)(r0g + rr) * 2 + o] = h0v * fcw[o * 2 + 0] + h1v * fcw[o * 2 + 1] + fcb[o];
  }
  for (int i = tid; i < 2 * 512; i += 512) {
    int rr = i >> 9, c = i & 511;
    float v;
    if (c < N0)            v = sA[rr][ID + c];           // hi(511)
    else if (c < N0 + N1)  v = sB[rr][c];                // hc(511)
    else                   v = sC[rr][N1 + (c - N0 - N1)]; // hm(511)
    out[512 + (size_t)(r0g + rr) * 512 + c] = v;
  }
}

extern "C" void kernel_launch(void* const* d_in, const int* in_sizes, int n_in,
                              void* d_out, int out_size, void* d_ws, size_t ws_size,
                              hipStream_t stream) {
  const float* x    = (const float*)d_in[0];
  const float* h0   = (const float*)d_in[1];
  const float* f1w0 = (const float*)d_in[2];
  const float* f1b0 = (const float*)d_in[3];
  const float* f2w0 = (const float*)d_in[4];
  const float* f2b0 = (const float*)d_in[5];
  const float* taw0 = (const float*)d_in[6];
  const float* tab0 = (const float*)d_in[7];
  const float* tbw0 = (const float*)d_in[8];
  const float* tbb0 = (const float*)d_in[9];
  const int*   m0   = (const int*)d_in[10];
  const float* f1w1 = (const float*)d_in[11];
  const float* f1b1 = (const float*)d_in[12];
  const float* f2w1 = (const float*)d_in[13];
  const float* f2b1 = (const float*)d_in[14];
  const float* taw1 = (const float*)d_in[15];
  const float* tab1 = (const float*)d_in[16];
  const float* tbw1 = (const float*)d_in[17];
  const float* tbb1 = (const float*)d_in[18];
  const int*   m1   = (const int*)d_in[19];
  const float* f1w2 = (const float*)d_in[20];
  const float* f1b2 = (const float*)d_in[21];
  const float* f2w2 = (const float*)d_in[22];
  const float* f2b2 = (const float*)d_in[23];
  const float* taw2 = (const float*)d_in[24];
  const float* tab2 = (const float*)d_in[25];
  const float* tbw2 = (const float*)d_in[26];
  const float* tbb2 = (const float*)d_in[27];
  const int*   m2   = (const int*)d_in[28];
  const float* fcw  = (const float*)d_in[29];
  const float* fcb  = (const float*)d_in[30];

  float* ws  = (float*)d_ws;
  float* out = (float*)d_out;

  // elements: 306*384 + 204*512 + 2*256 + 306 + 204 + 2 = 222,976 -> 871 blocks
  prep_kernel<<<871, 256, 0, stream>>>(
      f1w0, f2w0, taw0, tbw0, m0, f1b0, f2b0, tab0, tbb0,
      f1w1, f2w1, taw1, tbw1, m1, f1b1, f2b1, tab1, tbb1,
      f1w2, f2w2, taw2, tbw2, m2, f1b2, f2b2, tab2, tbb2,
      ws);

  lnn_main<<<128, 512, 0, stream>>>(
      x, h0, fcw, fcb,
      ws + OFF_WFFA, ws + OFF_WTDA, ws + OFF_BA,
      ws + OFF_WFFB, ws + OFF_WTDB, ws + OFF_BB,
      ws + OFF_WFFC, ws + OFF_WTDC, ws + OFF_BC,
      out);
}

// Round 5
// 52168.030 us; speedup vs baseline: 2.3233x; 1.0407x over previous
//
#include <hip/hip_runtime.h>
#include <hip/hip_fp16.h>

#define TSLEN 512
#define ID 64
#define N0 306
#define N1 204
#define N2 2
#define D0 370
#define D1 510
#define D2 206
#define D0P 376
#define D1P 512
#define D2P 208

// ws float-slot offsets
#define OFF_PFFA 0         // __half2[376*306]  (f1,f2) plane, [d][u] col-major
#define OFF_PTDA 115056    // __half [376*306]  td plane
#define OFF_PFFB 172584    // __half2[512*204]
#define OFF_PTDB 277032    // __half [512*204]
#define OFF_W2FF 329256    // float2[2*208]
#define OFF_W2TD 330088    // float [2*208]
#define OFF_BA   330504    // float4[306] (b1,b2,btd,0)
#define OFF_BB   331728    // float4[204]
#define OFF_B2   332544    // float4[2]
// total 332552 floats = 1.33 MB

__device__ __forceinline__ float cellact3(float a1, float a2, float at, float4 b) {
  float t1 = tanhf(a1 + b.x);
  float t2 = tanhf(a2 + b.y);
  float tv = 1.f / (1.f + __expf(-(at + b.z)));   // sigmoid(tb - ta)
  return t1 * (1.f - tv) + tv * t2;
}

__global__ __launch_bounds__(256) void prep_kernel(
    const float* __restrict__ f1w0, const float* __restrict__ f2w0,
    const float* __restrict__ taw0, const float* __restrict__ tbw0, const int* __restrict__ m0,
    const float* __restrict__ f1b0, const float* __restrict__ f2b0,
    const float* __restrict__ tab0, const float* __restrict__ tbb0,
    const float* __restrict__ f1w1, const float* __restrict__ f2w1,
    const float* __restrict__ taw1, const float* __restrict__ tbw1, const int* __restrict__ m1,
    const float* __restrict__ f1b1, const float* __restrict__ f2b1,
    const float* __restrict__ tab1, const float* __restrict__ tbb1,
    const float* __restrict__ f1w2, const float* __restrict__ f2w2,
    const float* __restrict__ taw2, const float* __restrict__ tbw2, const int* __restrict__ m2,
    const float* __restrict__ f1b2, const float* __restrict__ f2b2,
    const float* __restrict__ tab2, const float* __restrict__ tbb2,
    float* __restrict__ ws)
{
  int j = blockIdx.x * 256 + threadIdx.x;
  if (j < D0P * N0) {                       // layer 0 planes, [d][u]
    int d = j / N0, u = j - d * N0;
    float f1 = 0.f, f2 = 0.f, td = 0.f;
    if (d < D0) {
      int idx = u * D0 + d;
      float m = (float)m0[idx];
      f1 = f1w0[idx] * m; f2 = f2w0[idx] * m; td = tbw0[idx] - taw0[idx];
    }
    ((__half2*)(ws + OFF_PFFA))[j] = __floats2half2_rn(f1, f2);
    ((__half*)(ws + OFF_PTDA))[j]  = __float2half_rn(td);
    return;
  }
  j -= D0P * N0;
  if (j < D1P * N1) {                       // layer 1 planes
    int d = j / N1, u = j - d * N1;
    float f1 = 0.f, f2 = 0.f, td = 0.f;
    if (d < D1) {
      int idx = u * D1 + d;
      float m = (float)m1[idx];
      f1 = f1w1[idx] * m; f2 = f2w1[idx] * m; td = tbw1[idx] - taw1[idx];
    }
    ((__half2*)(ws + OFF_PFFB))[j] = __floats2half2_rn(f1, f2);
    ((__half*)(ws + OFF_PTDB))[j]  = __float2half_rn(td);
    return;
  }
  j -= D1P * N1;
  if (j < 2 * D2P) {                        // layer 2 (fp32, row-major [u][d])
    int u = j / D2P, d = j - u * D2P;
    float f1 = 0.f, f2 = 0.f, td = 0.f;
    if (d < D2) {
      int idx = u * D2 + d;
      float m = (float)m2[idx];
      f1 = f1w2[idx] * m; f2 = f2w2[idx] * m; td = tbw2[idx] - taw2[idx];
    }
    ((float2*)(ws + OFF_W2FF))[j] = make_float2(f1, f2);
    (ws + OFF_W2TD)[j] = td;
    return;
  }
  j -= 2 * D2P;
  if (j < N0) { ((float4*)(ws + OFF_BA))[j] = make_float4(f1b0[j], f2b0[j], tbb0[j] - tab0[j], 0.f); return; }
  j -= N0;
  if (j < N1) { ((float4*)(ws + OFF_BB))[j] = make_float4(f1b1[j], f2b1[j], tbb1[j] - tab1[j], 0.f); return; }
  j -= N1;
  if (j < N2) { ((float4*)(ws + OFF_B2))[j] = make_float4(f1b2[j], f2b2[j], tbb2[j] - tab2[j], 0.f); return; }
}

// 128 blocks x 2 rows; zero inter-block communication; weights streamed from L2,
// transposed so lane=unit (coalesced), k-reduce in-lane (no shuffles in hot loop).
__global__ __launch_bounds__(512) void lnn_main(
    const float* __restrict__ x, const float* __restrict__ h0,
    const float* __restrict__ fcw, const float* __restrict__ fcb,
    const float* __restrict__ ws, float* __restrict__ out)
{
  const __half2* __restrict__ PffA = (const __half2*)(ws + OFF_PFFA);
  const __half*  __restrict__ PtdA = (const __half*)(ws + OFF_PTDA);
  const __half2* __restrict__ PffB = (const __half2*)(ws + OFF_PFFB);
  const __half*  __restrict__ PtdB = (const __half*)(ws + OFF_PTDB);
  const float2*  __restrict__ W2ff = (const float2*)(ws + OFF_W2FF);
  const float*   __restrict__ W2td = ws + OFF_W2TD;
  const float4*  __restrict__ BA4  = (const float4*)(ws + OFF_BA);
  const float4*  __restrict__ BB4  = (const float4*)(ws + OFF_BB);
  const float4*  __restrict__ B24  = (const float4*)(ws + OFF_B2);

  __shared__ float sA[2][D0P];     // [x_t(64) | hi(306) | pad=0]
  __shared__ float sB[2][D1P];     // [hi(306) | hc_prev(204) | pad=0]
  __shared__ float sC[2][N1];      // hc(t) staging
  __shared__ float shm[2][2][2];   // hm double buffer [buf][row][unit]

  const int tid = threadIdx.x;
  const int wave = tid >> 6, lane = tid & 63;
  const int r0g = blockIdx.x * 2;

  // ---- init ----
  for (int i = tid; i < 2 * N0; i += 512) { int r = i >= N0; int u = i - (r ? N0 : 0); sB[r][u] = h0[(size_t)(r0g + r) * 512 + u]; }
  for (int i = tid; i < 2 * N1; i += 512) { int r = i >= N1; int u = i - (r ? N1 : 0); sC[r][u] = h0[(size_t)(r0g + r) * 512 + N0 + u]; }
  if (tid < 8) { int b = tid >> 2, r = (tid >> 1) & 1, u = tid & 1; shm[b][r][u] = h0[(size_t)(r0g + r) * 512 + N0 + N1 + u]; }
  if (tid < 2 * (D0P - D0)) { int r = tid >= (D0P - D0); sA[r][D0 + tid - (r ? (D0P - D0) : 0)] = 0.f; }
  if (tid < 2 * (D1P - (N0 + N1))) { int r = tid >= 2; sB[r][N0 + N1 + (tid & 1)] = 0.f; }
  __syncthreads();

  for (int t = 0; t < TSLEN; ++t) {
    // ---- staging ----
    if (tid < 128) { int r = tid >> 6, c = tid & 63; sA[r][c] = x[((size_t)(r0g + r) * TSLEN + t) * ID + c]; }
    for (int i = tid; i < 2 * N0; i += 512) { int r = i >= N0; int u = i - (r ? N0 : 0); sA[r][ID + u] = sB[r][u]; }
    for (int i = tid; i < 2 * N1; i += 512) { int r = i >= N1; int u = i - (r ? N1 : 0); sB[r][N0 + u] = sC[r][u]; }
    __syncthreads();

    // ---- phase A: hi(t), waves 0-4, lane = unit ----
    if (wave < 5) {
      int u = wave * 64 + lane;
      if (u < N0) {
        const __half2* pf = PffA + u;
        const __half*  pt = PtdA + u;
        float a10 = 0.f, a20 = 0.f, at0 = 0.f, a11 = 0.f, a21 = 0.f, at1 = 0.f;
        #pragma unroll 2
        for (int d = 0; d < D0P; d += 4) {
          float4 x0 = *(const float4*)&sA[0][d];
          float4 x1 = *(const float4*)&sA[1][d];
          #pragma unroll
          for (int j = 0; j < 4; ++j) {
            __half2 wf = pf[j * N0];
            float wt = __half2float(pt[j * N0]);
            float w1 = __low2float(wf), w2 = __high2float(wf);
            float xv0 = ((const float*)&x0)[j];
            float xv1 = ((const float*)&x1)[j];
            a10 = fmaf(w1, xv0, a10); a20 = fmaf(w2, xv0, a20); at0 = fmaf(wt, xv0, at0);
            a11 = fmaf(w1, xv1, a11); a21 = fmaf(w2, xv1, a21); at1 = fmaf(wt, xv1, at1);
          }
          pf += 4 * N0; pt += 4 * N0;
        }
        float4 b = BA4[u];
        sB[0][u] = cellact3(a10, a20, at0, b);
        sB[1][u] = cellact3(a11, a21, at1, b);
      }
    }
    __syncthreads();

    // ---- phase B: hc(t) on waves 0-3; lagged hm(t-1) on wave 7 ----
    if (wave < 4) {
      int u = wave * 64 + lane;
      if (u < N1) {
        const __half2* pf = PffB + u;
        const __half*  pt = PtdB + u;
        float a10 = 0.f, a20 = 0.f, at0 = 0.f, a11 = 0.f, a21 = 0.f, at1 = 0.f;
        #pragma unroll 2
        for (int d = 0; d < D1P; d += 4) {
          float4 x0 = *(const float4*)&sB[0][d];
          float4 x1 = *(const float4*)&sB[1][d];
          #pragma unroll
          for (int j = 0; j < 4; ++j) {
            __half2 wf = pf[j * N1];
            float wt = __half2float(pt[j * N1]);
            float w1 = __low2float(wf), w2 = __high2float(wf);
            float xv0 = ((const float*)&x0)[j];
            float xv1 = ((const float*)&x1)[j];
            a10 = fmaf(w1, xv0, a10); a20 = fmaf(w2, xv0, a20); at0 = fmaf(wt, xv0, at0);
            a11 = fmaf(w1, xv1, a11); a21 = fmaf(w2, xv1, a21); at1 = fmaf(wt, xv1, at1);
          }
          pf += 4 * N1; pt += 4 * N1;
        }
        float4 b = BB4[u];
        sC[0][u] = cellact3(a10, a20, at0, b);
        sC[1][u] = cellact3(a11, a21, at1, b);
      }
    } else if (wave == 7 && t > 0) {
      // hm(t-1) = cell2([hc(t-1), hm(t-2)]); hc(t-1) is sB cols 306..509
      int c = lane >> 2, ur = lane & 3, r = ur >> 1, u2 = ur & 1;
      int d0 = c * 13, dn = min(13, D2 - d0);
      int tbr = t & 1;                       // hm(t-2) buffer
      float a1 = 0.f, a2 = 0.f, at = 0.f;
      for (int jj = 0; jj < dn; ++jj) {
        int d = d0 + jj;
        float xv = (d < N1) ? sB[r][N0 + d] : shm[tbr][r][d - N1];
        float2 wf = W2ff[u2 * D2P + d];
        float wt = W2td[u2 * D2P + d];
        a1 = fmaf(wf.x, xv, a1); a2 = fmaf(wf.y, xv, a2); at = fmaf(wt, xv, at);
      }
      a1 += __shfl_xor(a1, 4);  a2 += __shfl_xor(a2, 4);  at += __shfl_xor(at, 4);
      a1 += __shfl_xor(a1, 8);  a2 += __shfl_xor(a2, 8);  at += __shfl_xor(at, 8);
      a1 += __shfl_xor(a1, 16); a2 += __shfl_xor(a2, 16); at += __shfl_xor(at, 16);
      a1 += __shfl_xor(a1, 32); a2 += __shfl_xor(a2, 32); at += __shfl_xor(at, 32);
      if (lane < 4) shm[(t - 1) & 1][r][u2] = cellact3(a1, a2, at, B24[u2]);
    }
    __syncthreads();
  }

  // ---- epilogue: hm(511) from hc(511) + hm(510) ----
  for (int i = tid; i < 2 * N1; i += 512) { int r = i >= N1; int u = i - (r ? N1 : 0); sB[r][N0 + u] = sC[r][u]; }
  __syncthreads();
  if (wave == 7) {
    int c = lane >> 2, ur = lane & 3, r = ur >> 1, u2 = ur & 1;
    int d0 = c * 13, dn = min(13, D2 - d0);
    float a1 = 0.f, a2 = 0.f, at = 0.f;
    for (int jj = 0; jj < dn; ++jj) {
      int d = d0 + jj;
      float xv = (d < N1) ? sB[r][N0 + d] : shm[0][r][d - N1];   // hm(510) in buf 0
      float2 wf = W2ff[u2 * D2P + d];
      float wt = W2td[u2 * D2P + d];
      a1 = fmaf(wf.x, xv, a1); a2 = fmaf(wf.y, xv, a2); at = fmaf(wt, xv, at);
    }
    a1 += __shfl_xor(a1, 4);  a2 += __shfl_xor(a2, 4);  at += __shfl_xor(at, 4);
    a1 += __shfl_xor(a1, 8);  a2 += __shfl_xor(a2, 8);  at += __shfl_xor(at, 8);
    a1 += __shfl_xor(a1, 16); a2 += __shfl_xor(a2, 16); at += __shfl_xor(at, 16);
    a1 += __shfl_xor(a1, 32); a2 += __shfl_xor(a2, 32); at += __shfl_xor(at, 32);
    if (lane < 4) shm[1][r][u2] = cellact3(a1, a2, at, B24[u2]);   // hm(511) -> buf 1
  }
  __syncthreads();

  if (tid < 4) {
    int r = tid >> 1, o = tid & 1;
    out[(size_t)(r0g + r) * 2 + o] =
        shm[1][r][0] * fcw[o * 2 + 0] + shm[1][r][1] * fcw[o * 2 + 1] + fcb[o];
  }
  for (int i = tid; i < 1024; i += 512) {
    int r = i >> 9, c = i & 511;
    float v = (c < N0) ? sB[r][c] : (c < N0 + N1) ? sC[r][c - N0] : shm[1][r][c - N0 - N1];
    out[512 + (size_t)(r0g + r) * 512 + c] = v;
  }
}

extern "C" void kernel_launch(void* const* d_in, const int* in_sizes, int n_in,
                              void* d_out, int out_size, void* d_ws, size_t ws_size,
                              hipStream_t stream) {
  const float* x    = (const float*)d_in[0];
  const float* h0   = (const float*)d_in[1];
  const float* f1w0 = (const float*)d_in[2];
  const float* f1b0 = (const float*)d_in[3];
  const float* f2w0 = (const float*)d_in[4];
  const float* f2b0 = (const float*)d_in[5];
  const float* taw0 = (const float*)d_in[6];
  const float* tab0 = (const float*)d_in[7];
  const float* tbw0 = (const float*)d_in[8];
  const float* tbb0 = (const float*)d_in[9];
  const int*   m0   = (const int*)d_in[10];
  const float* f1w1 = (const float*)d_in[11];
  const float* f1b1 = (const float*)d_in[12];
  const float* f2w1 = (const float*)d_in[13];
  const float* f2b1 = (const float*)d_in[14];
  const float* taw1 = (const float*)d_in[15];
  const float* tab1 = (const float*)d_in[16];
  const float* tbw1 = (const float*)d_in[17];
  const float* tbb1 = (const float*)d_in[18];
  const int*   m1   = (const int*)d_in[19];
  const float* f1w2 = (const float*)d_in[20];
  const float* f1b2 = (const float*)d_in[21];
  const float* f2w2 = (const float*)d_in[22];
  const float* f2b2 = (const float*)d_in[23];
  const float* taw2 = (const float*)d_in[24];
  const float* tab2 = (const float*)d_in[25];
  const float* tbw2 = (const float*)d_in[26];
  const float* tbb2 = (const float*)d_in[27];
  const int*   m2   = (const int*)d_in[28];
  const float* fcw  = (const float*)d_in[29];
  const float* fcb  = (const float*)d_in[30];

  float* ws  = (float*)d_ws;
  float* out = (float*)d_out;

  // items: 115056 + 104448 + 416 + 306 + 204 + 2 = 220432 -> 862 blocks
  prep_kernel<<<862, 256, 0, stream>>>(
      f1w0, f2w0, taw0, tbw0, m0, f1b0, f2b0, tab0, tbb0,
      f1w1, f2w1, taw1, tbw1, m1, f1b1, f2b1, tab1, tbb1,
      f1w2, f2w2, taw2, tbw2, m2, f1b2, f2b2, tab2, tbb2,
      ws);

  lnn_main<<<128, 512, 0, stream>>>(x, h0, fcw, fcb, ws, out);
}

// Round 6
// 27023.630 us; speedup vs baseline: 4.4850x; 1.9305x over previous
//
#include <hip/hip_runtime.h>
#include <hip/hip_fp16.h>

typedef unsigned int u32;
typedef _Float16 h2v __attribute__((ext_vector_type(2)));

#define TSLEN 512
#define N0 306
#define N1 204
#define D0 370
#define D1 510
#define D2 206

// ws dword offsets
#define OFF_WA1 0          // u32[306*186] half2 pairs (ff1 plane, [u][pair])
#define OFF_WA2 56916
#define OFF_WAT 113832
#define OFF_WB1 170748     // u32[204*256]
#define OFF_WB2 222972
#define OFF_WBT 275196
#define OFF_WC1 327420     // f32[2*208]
#define OFF_WC2 327836
#define OFF_WCT 328252
#define OFF_BA  328668     // float4[306]
#define OFF_BB  329892     // float4[204]
#define OFF_B2  330708     // float4[2]
// total 330716 dwords = 1.29 MB

__device__ __forceinline__ u32 packh2(float a, float b) {
  __half2 h = __floats2half2_rn(a, b);
  return __builtin_bit_cast(u32, h);
}

__device__ __forceinline__ float dot2(u32 w, u32 xx, float acc) {
  return __builtin_amdgcn_fdot2(__builtin_bit_cast(h2v, w), __builtin_bit_cast(h2v, xx), acc, false);
}

__device__ __forceinline__ float cellact3(float a1, float a2, float at, float4 b) {
  float t1 = tanhf(a1 + b.x);
  float t2 = tanhf(a2 + b.y);
  float tv = 1.f / (1.f + __expf(-(at + b.z)));   // sigmoid(tb - ta)
  return t1 * (1.f - tv) + tv * t2;
}

__global__ __launch_bounds__(256) void prep_kernel(
    const float* __restrict__ f1w0, const float* __restrict__ f2w0,
    const float* __restrict__ taw0, const float* __restrict__ tbw0, const int* __restrict__ m0,
    const float* __restrict__ f1b0, const float* __restrict__ f2b0,
    const float* __restrict__ tab0, const float* __restrict__ tbb0,
    const float* __restrict__ f1w1, const float* __restrict__ f2w1,
    const float* __restrict__ taw1, const float* __restrict__ tbw1, const int* __restrict__ m1,
    const float* __restrict__ f1b1, const float* __restrict__ f2b1,
    const float* __restrict__ tab1, const float* __restrict__ tbb1,
    const float* __restrict__ f1w2, const float* __restrict__ f2w2,
    const float* __restrict__ taw2, const float* __restrict__ tbw2, const int* __restrict__ m2,
    const float* __restrict__ f1b2, const float* __restrict__ f2b2,
    const float* __restrict__ tab2, const float* __restrict__ tbb2,
    float* __restrict__ ws)
{
  int j = blockIdx.x * 256 + threadIdx.x;
  u32* W = (u32*)ws;
  if (j < 306 * 186) {                 // layer A planes
    int u = j / 186, p = j - u * 186;
    float f1a = 0.f, f1b_ = 0.f, f2a = 0.f, f2b_ = 0.f, ta = 0.f, tb = 0.f;
    int d0 = 2 * p, d1 = 2 * p + 1;
    if (d0 < D0) { int i = u * D0 + d0; float m = (float)m0[i]; f1a = f1w0[i]*m; f2a = f2w0[i]*m; ta = tbw0[i]-taw0[i]; }
    if (d1 < D0) { int i = u * D0 + d1; float m = (float)m0[i]; f1b_ = f1w0[i]*m; f2b_ = f2w0[i]*m; tb = tbw0[i]-taw0[i]; }
    W[OFF_WA1 + j] = packh2(f1a, f1b_);
    W[OFF_WA2 + j] = packh2(f2a, f2b_);
    W[OFF_WAT + j] = packh2(ta, tb);
    return;
  }
  j -= 306 * 186;
  if (j < 204 * 256) {                 // layer B planes
    int u = j / 256, p = j - u * 256;
    float f1a = 0.f, f1b_ = 0.f, f2a = 0.f, f2b_ = 0.f, ta = 0.f, tb = 0.f;
    int d0 = 2 * p, d1 = 2 * p + 1;
    if (d0 < D1) { int i = u * D1 + d0; float m = (float)m1[i]; f1a = f1w1[i]*m; f2a = f2w1[i]*m; ta = tbw1[i]-taw1[i]; }
    if (d1 < D1) { int i = u * D1 + d1; float m = (float)m1[i]; f1b_ = f1w1[i]*m; f2b_ = f2w1[i]*m; tb = tbw1[i]-taw1[i]; }
    W[OFF_WB1 + j] = packh2(f1a, f1b_);
    W[OFF_WB2 + j] = packh2(f2a, f2b_);
    W[OFF_WBT + j] = packh2(ta, tb);
    return;
  }
  j -= 204 * 256;
  if (j < 2 * 208) {                   // layer C planes (fp32)
    int u = j / 208, d = j - u * 208;
    float f1 = 0.f, f2 = 0.f, td = 0.f;
    if (d < D2) { int i = u * D2 + d; float m = (float)m2[i]; f1 = f1w2[i]*m; f2 = f2w2[i]*m; td = tbw2[i]-taw2[i]; }
    ws[OFF_WC1 + j] = f1; ws[OFF_WC2 + j] = f2; ws[OFF_WCT + j] = td;
    return;
  }
  j -= 2 * 208;
  if (j < 306) { ((float4*)(ws + OFF_BA))[j] = make_float4(f1b0[j], f2b0[j], tbb0[j] - tab0[j], 0.f); return; }
  j -= 306;
  if (j < 204) { ((float4*)(ws + OFF_BB))[j] = make_float4(f1b1[j], f2b1[j], tbb1[j] - tab1[j], 0.f); return; }
  j -= 204;
  if (j < 2)   { ((float4*)(ws + OFF_B2))[j] = make_float4(f1b2[j], f2b2[j], tbb2[j] - tab2[j], 0.f); return; }
}

// One block (1024 thr) = one batch row. ALL weights resident in VGPRs.
// Per step: 4 barriers, LDS partial-sum reductions, zero weight memory traffic.
__global__ __launch_bounds__(1024, 1) void lnn_main(
    const float* __restrict__ x, const float* __restrict__ h0,
    const float* __restrict__ fcw, const float* __restrict__ fcb,
    const float* __restrict__ ws, float* __restrict__ out)
{
  __shared__ uint2 XAh2[94];     // [x(64)|hi(306)|pad2] as half pairs (93 uint2 used)
  __shared__ uint2 XBh2[128];    // [hi(306)|hc(204)|pad2] as half pairs
  __shared__ float XB32[512];    // f32: [hi(306)|hc(204)|pad2]
  __shared__ float pA[918 * 3];
  __shared__ float pB[204 * 13];
  __shared__ float shm2[2];

  const int tid = threadIdx.x;
  const int row = blockIdx.x;
  const u32* W = (const u32*)ws;

  // ---- static assignments ----
  const int uA = tid / 3, sA_ = tid - uA * 3;     // valid tid<918: unit, k-span(124)
  const int uB = tid >> 2, sB_ = tid & 3;         // valid tid<816: unit, k-span(128)
  const int l15 = tid - 960, u2 = l15 & 1, ch = l15 >> 1;   // wave 15: layer C

  // ---- weight registers ----
  u32 wa1[31], wa2[31], wat[31];
  u32 wb1[32], wb2[32], wbt[32];
  float wc1[7], wc2[7], wct[7];
  float4 ba, bb, b2;
  float hm0 = 0.f, hm1 = 0.f;

  if (tid < 918) {
    const u32* p1 = W + OFF_WA1 + uA * 186 + sA_ * 62;
    const u32* p2 = W + OFF_WA2 + uA * 186 + sA_ * 62;
    const u32* p3 = W + OFF_WAT + uA * 186 + sA_ * 62;
    #pragma unroll
    for (int j = 0; j < 31; ++j) {
      wa1[2*j >= 62 ? 0 : j] = 0;  // (dummy to keep pattern simple)
    }
    #pragma unroll
    for (int j = 0; j < 31; ++j) { wa1[j] = p1[2*j] | 0; }
    #pragma unroll
    for (int j = 0; j < 31; ++j) { wa1[j] = p1[j*2]; }
    // NOTE: loads done properly below (uint2 granularity)
    #pragma unroll
    for (int j = 0; j < 31; ++j) {
      wa1[j] = p1[2*j];
    }
    (void)0;
  }
  // ---- clean weight loads (dword pairs kept as two u32 per iter) ----
  if (tid < 918) {
    const u32* p1 = W + OFF_WA1 + uA * 186 + sA_ * 62;
    const u32* p2 = W + OFF_WA2 + uA * 186 + sA_ * 62;
    const u32* p3 = W + OFF_WAT + uA * 186 + sA_ * 62;
    #pragma unroll
    for (int j = 0; j < 31; ++j) {
      uint2 v1 = ((const uint2*)p1)[j]; wa1[j] = v1.x;  // store even; odd handled via second array slot
      (void)v1;
    }
    (void)p2; (void)p3;
  }
  // The above experimentation is replaced by the real scheme: keep 62 dwords
  // per plane as 31 uint2 loads feeding u32 pairs (even/odd interleave).
  u32 wa1o[31], wa2o[31], wato[31];
  u32 wb1o[32], wb2o[32], wbto[32];
  if (tid < 918) {
    const uint2* p1 = (const uint2*)(W + OFF_WA1 + uA * 186 + sA_ * 62);
    const uint2* p2 = (const uint2*)(W + OFF_WA2 + uA * 186 + sA_ * 62);
    const uint2* p3 = (const uint2*)(W + OFF_WAT + uA * 186 + sA_ * 62);
    #pragma unroll
    for (int j = 0; j < 31; ++j) {
      uint2 v1 = p1[j], v2 = p2[j], v3 = p3[j];
      wa1[j] = v1.x; wa1o[j] = v1.y;
      wa2[j] = v2.x; wa2o[j] = v2.y;
      wat[j] = v3.x; wato[j] = v3.y;
    }
  }
  if (tid < 816) {
    const uint2* p1 = (const uint2*)(W + OFF_WB1 + uB * 256 + sB_ * 64);
    const uint2* p2 = (const uint2*)(W + OFF_WB2 + uB * 256 + sB_ * 64);
    const uint2* p3 = (const uint2*)(W + OFF_WBT + uB * 256 + sB_ * 64);
    #pragma unroll
    for (int j = 0; j < 32; ++j) {
      uint2 v1 = p1[j], v2 = p2[j], v3 = p3[j];
      wb1[j] = v1.x; wb1o[j] = v1.y;
      wb2[j] = v2.x; wb2o[j] = v2.y;
      wbt[j] = v3.x; wbto[j] = v3.y;
    }
  }
  if (tid < 306) ba = ((const float4*)(ws + OFF_BA))[tid];
  if (tid < 204) bb = ((const float4*)(ws + OFF_BB))[tid];
  if (tid >= 960) {
    #pragma unroll
    for (int j = 0; j < 7; ++j) {
      int d = ch * 7 + j;
      bool ok = d < 208;
      wc1[j] = ok ? ws[OFF_WC1 + u2 * 208 + d] : 0.f;
      wc2[j] = ok ? ws[OFF_WC2 + u2 * 208 + d] : 0.f;
      wct[j] = ok ? ws[OFF_WCT + u2 * 208 + d] : 0.f;
    }
    b2 = ((const float4*)(ws + OFF_B2))[u2];
    hm0 = h0[(size_t)row * 512 + 510];
    hm1 = h0[(size_t)row * 512 + 511];
  }

  // ---- init state ----
  __half* XAh = (__half*)XAh2;
  __half* XBh = (__half*)XBh2;
  if (tid < 306) {
    float v = h0[(size_t)row * 512 + tid];
    XAh[64 + tid] = __float2half(v);
  }
  if (tid < 204) {
    float v = h0[(size_t)row * 512 + 306 + tid];
    XBh[306 + tid] = __float2half(v);
    XB32[306 + tid] = v;
  }
  if (tid < 2) { XAh[370 + tid] = __float2half(0.f); XBh[510 + tid] = __float2half(0.f); XB32[510 + tid] = 0.f; }
  __syncthreads();

  // ---- recurrence ----
  for (int t = 0; t < TSLEN; ++t) {
    // phase 1: B-finish(t-1) on lanes<204; x_t staging on lanes 204..235
    if (t > 0 && tid < 204) {
      int b = tid * 13;
      float a1 = pB[b+0] + pB[b+3] + pB[b+6] + pB[b+9];
      float a2 = pB[b+1] + pB[b+4] + pB[b+7] + pB[b+10];
      float at = pB[b+2] + pB[b+5] + pB[b+8] + pB[b+11];
      float hc = cellact3(a1, a2, at, bb);
      XB32[306 + tid] = hc;
      XBh[306 + tid] = __float2half(hc);
    } else if (tid >= 204 && tid < 236) {
      int i = tid - 204;
      float2 xv = *(const float2*)(x + ((size_t)row * TSLEN + t) * 64 + 2 * i);
      ((u32*)XAh2)[i] = packh2(xv.x, xv.y);
    }
    __syncthreads();

    // phase 2: A-partials (lanes<918) + lagged layer C on wave 15
    if (tid < 918) {
      float a1 = 0.f, a2 = 0.f, at = 0.f;
      const uint2* xs = XAh2 + sA_ * 31;
      #pragma unroll
      for (int j = 0; j < 31; ++j) {
        uint2 xq = xs[j];
        a1 = dot2(wa1[j], xq.x, a1); a1 = dot2(wa1o[j], xq.y, a1);
        a2 = dot2(wa2[j], xq.x, a2); a2 = dot2(wa2o[j], xq.y, a2);
        at = dot2(wat[j], xq.x, at); at = dot2(wato[j], xq.y, at);
      }
      pA[tid * 3 + 0] = a1; pA[tid * 3 + 1] = a2; pA[tid * 3 + 2] = at;
    } else if (tid >= 960 && t > 0) {
      float a1 = 0.f, a2 = 0.f, at = 0.f;
      #pragma unroll
      for (int j = 0; j < 7; ++j) {
        int d = ch * 7 + j;
        float xv = (d < 204) ? XB32[306 + d] : (d == 204 ? hm0 : (d == 205 ? hm1 : 0.f));
        a1 = fmaf(wc1[j], xv, a1); a2 = fmaf(wc2[j], xv, a2); at = fmaf(wct[j], xv, at);
      }
      #pragma unroll
      for (int m = 2; m <= 32; m <<= 1) {
        a1 += __shfl_xor(a1, m); a2 += __shfl_xor(a2, m); at += __shfl_xor(at, m);
      }
      float hmn = cellact3(a1, a2, at, b2);
      float other = __shfl_xor(hmn, 1);
      hm0 = (u2 == 0) ? hmn : other;
      hm1 = (u2 == 0) ? other : hmn;
    }
    __syncthreads();

    // phase 3: A-finish -> hi(t)
    if (tid < 306) {
      int b = tid * 9;
      float a1 = pA[b+0] + pA[b+3] + pA[b+6];
      float a2 = pA[b+1] + pA[b+4] + pA[b+7];
      float at = pA[b+2] + pA[b+5] + pA[b+8];
      float hi = cellact3(a1, a2, at, ba);
      XB32[tid] = hi;
      __half hh = __float2half(hi);
      XBh[tid] = hh;
      XAh[64 + tid] = hh;
    }
    __syncthreads();

    // phase 4: B-partials (lanes<816)
    if (tid < 816) {
      float a1 = 0.f, a2 = 0.f, at = 0.f;
      const uint2* xs = XBh2 + sB_ * 32;
      #pragma unroll
      for (int j = 0; j < 32; ++j) {
        uint2 xq = xs[j];
        a1 = dot2(wb1[j], xq.x, a1); a1 = dot2(wb1o[j], xq.y, a1);
        a2 = dot2(wb2[j], xq.x, a2); a2 = dot2(wb2o[j], xq.y, a2);
        at = dot2(wbt[j], xq.x, at); at = dot2(wbto[j], xq.y, at);
      }
      pB[uB * 13 + sB_ * 3 + 0] = a1;
      pB[uB * 13 + sB_ * 3 + 1] = a2;
      pB[uB * 13 + sB_ * 3 + 2] = at;
    }
    __syncthreads();
  }

  // ---- epilogue ----
  if (tid < 204) {   // B-finish for t=511 -> hc(511)
    int b = tid * 13;
    float a1 = pB[b+0] + pB[b+3] + pB[b+6] + pB[b+9];
    float a2 = pB[b+1] + pB[b+4] + pB[b+7] + pB[b+10];
    float at = pB[b+2] + pB[b+5] + pB[b+8] + pB[b+11];
    XB32[306 + tid] = cellact3(a1, a2, at, bb);
  }
  __syncthreads();
  if (tid >= 960) {  // hm(511) from hc(511) + hm(510)
    float a1 = 0.f, a2 = 0.f, at = 0.f;
    #pragma unroll
    for (int j = 0; j < 7; ++j) {
      int d = ch * 7 + j;
      float xv = (d < 204) ? XB32[306 + d] : (d == 204 ? hm0 : (d == 205 ? hm1 : 0.f));
      a1 = fmaf(wc1[j], xv, a1); a2 = fmaf(wc2[j], xv, a2); at = fmaf(wct[j], xv, at);
    }
    #pragma unroll
    for (int m = 2; m <= 32; m <<= 1) {
      a1 += __shfl_xor(a1, m); a2 += __shfl_xor(a2, m); at += __shfl_xor(at, m);
    }
    float hmn = cellact3(a1, a2, at, b2);
    if (l15 < 2) shm2[u2] = hmn;
  }
  __syncthreads();

  if (tid < 2) {
    int o = tid;
    out[(size_t)row * 2 + o] = shm2[0] * fcw[o * 2 + 0] + shm2[1] * fcw[o * 2 + 1] + fcb[o];
  }
  if (tid < 512) {
    float v = (tid < 510) ? XB32[tid] : shm2[tid - 510];
    out[512 + (size_t)row * 512 + tid] = v;
  }
}

extern "C" void kernel_launch(void* const* d_in, const int* in_sizes, int n_in,
                              void* d_out, int out_size, void* d_ws, size_t ws_size,
                              hipStream_t stream) {
  const float* x    = (const float*)d_in[0];
  const float* h0   = (const float*)d_in[1];
  const float* f1w0 = (const float*)d_in[2];
  const float* f1b0 = (const float*)d_in[3];
  const float* f2w0 = (const float*)d_in[4];
  const float* f2b0 = (const float*)d_in[5];
  const float* taw0 = (const float*)d_in[6];
  const float* tab0 = (const float*)d_in[7];
  const float* tbw0 = (const float*)d_in[8];
  const float* tbb0 = (const float*)d_in[9];
  const int*   m0   = (const int*)d_in[10];
  const float* f1w1 = (const float*)d_in[11];
  const float* f1b1 = (const float*)d_in[12];
  const float* f2w1 = (const float*)d_in[13];
  const float* f2b1 = (const float*)d_in[14];
  const float* taw1 = (const float*)d_in[15];
  const float* tab1 = (const float*)d_in[16];
  const float* tbw1 = (const float*)d_in[17];
  const float* tbb1 = (const float*)d_in[18];
  const int*   m1   = (const int*)d_in[19];
  const float* f1w2 = (const float*)d_in[20];
  const float* f1b2 = (const float*)d_in[21];
  const float* f2w2 = (const float*)d_in[22];
  const float* f2b2 = (const float*)d_in[23];
  const float* taw2 = (const float*)d_in[24];
  const float* tab2 = (const float*)d_in[25];
  const float* tbw2 = (const float*)d_in[26];
  const float* tbb2 = (const float*)d_in[27];
  const int*   m2   = (const int*)d_in[28];
  const float* fcw  = (const float*)d_in[29];
  const float* fcb  = (const float*)d_in[30];

  float* ws  = (float*)d_ws;
  float* out = (float*)d_out;

  // total prep items: 56916 + 52224 + 416 + 306 + 204 + 2 = 110068
  prep_kernel<<<431, 256, 0, stream>>>(
      f1w0, f2w0, taw0, tbw0, m0, f1b0, f2b0, tab0, tbb0,
      f1w1, f2w1, taw1, tbw1, m1, f1b1, f2b1, tab1, tbb1,
      f1w2, f2w2, taw2, tbw2, m2, f1b2, f2b2, tab2, tbb2,
      ws);

  lnn_main<<<256, 1024, 0, stream>>>(x, h0, fcw, fcb, ws, out);
}

// Round 7
// 13596.362 us; speedup vs baseline: 8.9143x; 1.9876x over previous
//
#include <hip/hip_runtime.h>
#include <hip/hip_fp16.h>

typedef unsigned int u32;
typedef _Float16 h2v __attribute__((ext_vector_type(2)));

#define TSLEN 512
#define N0 306
#define N1 204
#define D0 370
#define D1 510
#define D2 206

// ws u32/f32 offsets
#define OFF_WA  0          // uint4[48][918]  layer-A planes (plane-major, lane-coalesced)
#define OFF_WB  176256     // uint4[48][816]  layer-B planes
#define OFF_WC1 332928     // f32[2][208]
#define OFF_WC2 333344
#define OFF_WCT 333760
#define OFF_BA  334176     // float4[306]
#define OFF_BB  335400     // float4[204]
#define OFF_B2  336216     // float4[2]
// total 336224 dwords = 1.34 MB

__device__ __forceinline__ u32 packh2(float a, float b) {
  __half2 h = __floats2half2_rn(a, b);
  return __builtin_bit_cast(u32, h);
}

__device__ __forceinline__ float dot2(u32 w, u32 xx, float acc) {
  return __builtin_amdgcn_fdot2(__builtin_bit_cast(h2v, w), __builtin_bit_cast(h2v, xx), acc, false);
}

__device__ __forceinline__ float cellact3(float a1, float a2, float at, float4 b) {
  float t1 = tanhf(a1 + b.x);
  float t2 = tanhf(a2 + b.y);
  float tv = 1.f / (1.f + __expf(-(at + b.z)));   // sigmoid(tb - ta)
  return t1 * (1.f - tv) + tv * t2;
}

// 8 coalesced uint4 weight loads (stride STR uint4s) + 32 fdot2 against reg-held x.
template<int STR>
__device__ __forceinline__ float dot8(const uint4* __restrict__ wp, const uint4 (&xv)[8], float a) {
  uint4 wv[8];
  #pragma unroll
  for (int j = 0; j < 8; ++j) wv[j] = wp[j * STR];
  #pragma unroll
  for (int j = 0; j < 8; ++j) {
    a = dot2(wv[j].x, xv[j].x, a);
    a = dot2(wv[j].y, xv[j].y, a);
    a = dot2(wv[j].z, xv[j].z, a);
    a = dot2(wv[j].w, xv[j].w, a);
  }
  return a;
}

__global__ __launch_bounds__(256) void prep_kernel(
    const float* __restrict__ f1w0, const float* __restrict__ f2w0,
    const float* __restrict__ taw0, const float* __restrict__ tbw0, const int* __restrict__ m0,
    const float* __restrict__ f1b0, const float* __restrict__ f2b0,
    const float* __restrict__ tab0, const float* __restrict__ tbb0,
    const float* __restrict__ f1w1, const float* __restrict__ f2w1,
    const float* __restrict__ taw1, const float* __restrict__ tbw1, const int* __restrict__ m1,
    const float* __restrict__ f1b1, const float* __restrict__ f2b1,
    const float* __restrict__ tab1, const float* __restrict__ tbb1,
    const float* __restrict__ f1w2, const float* __restrict__ f2w2,
    const float* __restrict__ taw2, const float* __restrict__ tbw2, const int* __restrict__ m2,
    const float* __restrict__ f1b2, const float* __restrict__ f2b2,
    const float* __restrict__ tab2, const float* __restrict__ tbb2,
    float* __restrict__ ws)
{
  int j = blockIdx.x * 256 + threadIdx.x;
  u32* W = (u32*)ws;
  if (j < 176256) {                       // layer A: q -> [plane*16+jj][u*3+s] uint4, component c
    int q4 = j >> 2, c = j & 3;
    int jq = q4 / 918, us = q4 - jq * 918;
    int u = us / 3, s = us - u * 3;
    int plane = jq >> 4, jj = jq & 15;
    int p = s * 64 + jj * 4 + c;          // k-pair index in padded 384-k space
    int k0 = 2 * p, k1 = 2 * p + 1;
    float v0 = 0.f, v1 = 0.f;
    if (k0 < D0) {
      int i = u * D0 + k0;
      v0 = (plane == 0) ? f1w0[i] * (float)m0[i]
         : (plane == 1) ? f2w0[i] * (float)m0[i]
                        : tbw0[i] - taw0[i];
    }
    if (k1 < D0) {
      int i = u * D0 + k1;
      v1 = (plane == 0) ? f1w0[i] * (float)m0[i]
         : (plane == 1) ? f2w0[i] * (float)m0[i]
                        : tbw0[i] - taw0[i];
    }
    W[OFF_WA + j] = packh2(v0, v1);
    return;
  }
  j -= 176256;
  if (j < 156672) {                       // layer B: [plane*16+jj][u*4+s]
    int q4 = j >> 2, c = j & 3;
    int jq = q4 / 816, us = q4 - jq * 816;
    int u = us >> 2, s = us & 3;
    int plane = jq >> 4, jj = jq & 15;
    int p = s * 64 + jj * 4 + c;          // padded 512-k space
    int k0 = 2 * p, k1 = 2 * p + 1;
    float v0 = 0.f, v1 = 0.f;
    if (k0 < D1) {
      int i = u * D1 + k0;
      v0 = (plane == 0) ? f1w1[i] * (float)m1[i]
         : (plane == 1) ? f2w1[i] * (float)m1[i]
                        : tbw1[i] - taw1[i];
    }
    if (k1 < D1) {
      int i = u * D1 + k1;
      v1 = (plane == 0) ? f1w1[i] * (float)m1[i]
         : (plane == 1) ? f2w1[i] * (float)m1[i]
                        : tbw1[i] - taw1[i];
    }
    W[OFF_WB + j] = packh2(v0, v1);
    return;
  }
  j -= 156672;
  if (j < 416) {                          // layer C (fp32 [u][208])
    int u = j / 208, d = j - u * 208;
    float f1 = 0.f, f2 = 0.f, td = 0.f;
    if (d < D2) { int i = u * D2 + d; float m = (float)m2[i]; f1 = f1w2[i]*m; f2 = f2w2[i]*m; td = tbw2[i]-taw2[i]; }
    ws[OFF_WC1 + j] = f1; ws[OFF_WC2 + j] = f2; ws[OFF_WCT + j] = td;
    return;
  }
  j -= 416;
  if (j < 306) { ((float4*)(ws + OFF_BA))[j] = make_float4(f1b0[j], f2b0[j], tbb0[j] - tab0[j], 0.f); return; }
  j -= 306;
  if (j < 204) { ((float4*)(ws + OFF_BB))[j] = make_float4(f1b1[j], f2b1[j], tbb1[j] - tab1[j], 0.f); return; }
  j -= 204;
  if (j < 2)   { ((float4*)(ws + OFF_B2))[j] = make_float4(f1b2[j], f2b2[j], tbb2[j] - tab2[j], 0.f); return; }
}

// One block (1024 thr) = one batch row. Weights streamed from ws (L2-shared image)
// every step via coalesced b128 loads; x/state in LDS (half2), partials via LDS.
__global__ __launch_bounds__(1024, 1) void lnn_main(
    const float* __restrict__ x, const float* __restrict__ h0,
    const float* __restrict__ fcw, const float* __restrict__ fcb,
    const float* __restrict__ ws, float* __restrict__ out)
{
  __shared__ uint4 XA4[48];      // [x(64)|hi(306)|pad] as half2, 3 spans x 16 uint4
  __shared__ uint4 XB4[64];      // [hi(306)|hc(204)|pad], 4 spans x 16 uint4
  __shared__ float XB32[512];    // f32 copies: hi(306) | hc(204) | pad
  __shared__ float pA[918 * 3];
  __shared__ float pB[204 * 13];
  __shared__ float shm2[2];

  const int tid = threadIdx.x;
  const int row = blockIdx.x;

  const int sA_ = tid % 3;                  // A: tid = u*3 + s, tid < 918
  const int uB = tid >> 2, sB_ = tid & 3;   // B: tid = u*4 + s, tid < 816
  const int l15 = tid - 960, u2 = l15 & 1, ch = l15 >> 1;   // wave 15: layer C

  const uint4* __restrict__ WA4 = (const uint4*)((const u32*)ws + OFF_WA);
  const uint4* __restrict__ WB4 = (const uint4*)((const u32*)ws + OFF_WB);
  const float4* BA4 = (const float4*)(ws + OFF_BA);
  const float4* BB4 = (const float4*)(ws + OFF_BB);
  const float4* B24 = (const float4*)(ws + OFF_B2);

  __half* XAh = (__half*)XA4;
  __half* XBh = (__half*)XB4;

  float4 ba = make_float4(0.f,0.f,0.f,0.f), bb = make_float4(0.f,0.f,0.f,0.f), b2 = make_float4(0.f,0.f,0.f,0.f);
  float wc1[7], wc2[7], wct[7];
  float hm0 = 0.f, hm1 = 0.f;

  if (tid < 306) ba = BA4[tid];
  if (tid < 204) bb = BB4[tid];
  if (tid >= 960) {
    #pragma unroll
    for (int j = 0; j < 7; ++j) {
      int d = ch * 7 + j;
      bool ok = d < 208;
      wc1[j] = ok ? ws[OFF_WC1 + u2 * 208 + d] : 0.f;
      wc2[j] = ok ? ws[OFF_WC2 + u2 * 208 + d] : 0.f;
      wct[j] = ok ? ws[OFF_WCT + u2 * 208 + d] : 0.f;
    }
    b2 = B24[u2];
    hm0 = h0[(size_t)row * 512 + 510];
    hm1 = h0[(size_t)row * 512 + 511];
  }

  // ---- init LDS state ----
  if (tid < 306) {
    float v = h0[(size_t)row * 512 + tid];
    XAh[64 + tid] = __float2half(v);
  }
  if (tid < 204) {
    float v = h0[(size_t)row * 512 + 306 + tid];
    XBh[306 + tid] = __float2half(v);
    XB32[306 + tid] = v;
  }
  if (tid < 14) XAh[370 + tid] = __float2half(0.f);   // pad k 370..383
  if (tid >= 14 && tid < 16) XBh[510 + (tid - 14)] = __float2half(0.f);
  __syncthreads();

  for (int t = 0; t < TSLEN; ++t) {
    // ---- phase 1: B-finish(t-1) on tid<204; x_t staging on tid 204..235 ----
    if (t > 0 && tid < 204) {
      int b = tid * 13;
      float a1 = pB[b+0] + pB[b+3] + pB[b+6] + pB[b+9];
      float a2 = pB[b+1] + pB[b+4] + pB[b+7] + pB[b+10];
      float at = pB[b+2] + pB[b+5] + pB[b+8] + pB[b+11];
      float hc = cellact3(a1, a2, at, bb);
      XB32[306 + tid] = hc;
      XBh[306 + tid] = __float2half(hc);
    } else if (tid >= 204 && tid < 236) {
      int i = tid - 204;
      float2 xv = *(const float2*)(x + ((size_t)row * TSLEN + t) * 64 + 2 * i);
      ((u32*)XA4)[i] = packh2(xv.x, xv.y);
    }
    __syncthreads();

    // ---- phase 2: A-partials (tid<918, streamed weights) + lagged layer C (wave 15) ----
    if (tid < 918) {
      const uint4* wp = WA4 + tid;
      const uint4* xs = XA4 + sA_ * 16;
      float a1 = 0.f, a2 = 0.f, at = 0.f;
      #pragma unroll
      for (int h = 0; h < 2; ++h) {
        uint4 xv[8];
        #pragma unroll
        for (int j = 0; j < 8; ++j) xv[j] = xs[h * 8 + j];
        a1 = dot8<918>(wp + (0 * 16 + h * 8) * 918, xv, a1);
        a2 = dot8<918>(wp + (1 * 16 + h * 8) * 918, xv, a2);
        at = dot8<918>(wp + (2 * 16 + h * 8) * 918, xv, at);
      }
      pA[tid * 3 + 0] = a1; pA[tid * 3 + 1] = a2; pA[tid * 3 + 2] = at;
    } else if (tid >= 960 && t > 0) {
      float a1 = 0.f, a2 = 0.f, at = 0.f;
      #pragma unroll
      for (int j = 0; j < 7; ++j) {
        int d = ch * 7 + j;
        float xv = (d < 204) ? XB32[306 + d] : (d == 204 ? hm0 : (d == 205 ? hm1 : 0.f));
        a1 = fmaf(wc1[j], xv, a1); a2 = fmaf(wc2[j], xv, a2); at = fmaf(wct[j], xv, at);
      }
      #pragma unroll
      for (int m = 2; m <= 32; m <<= 1) {
        a1 += __shfl_xor(a1, m); a2 += __shfl_xor(a2, m); at += __shfl_xor(at, m);
      }
      float hmn = cellact3(a1, a2, at, b2);
      float other = __shfl_xor(hmn, 1);
      hm0 = (u2 == 0) ? hmn : other;
      hm1 = (u2 == 0) ? other : hmn;
    }
    __syncthreads();

    // ---- phase 3: A-finish -> hi(t) ----
    if (tid < 306) {
      int b = tid * 9;
      float a1 = pA[b+0] + pA[b+3] + pA[b+6];
      float a2 = pA[b+1] + pA[b+4] + pA[b+7];
      float at = pA[b+2] + pA[b+5] + pA[b+8];
      float hi = cellact3(a1, a2, at, ba);
      XB32[tid] = hi;
      __half hh = __float2half(hi);
      XBh[tid] = hh;
      XAh[64 + tid] = hh;
    }
    __syncthreads();

    // ---- phase 4: B-partials (tid<816, streamed weights) ----
    if (tid < 816) {
      const uint4* wp = WB4 + tid;
      const uint4* xs = XB4 + sB_ * 16;
      float a1 = 0.f, a2 = 0.f, at = 0.f;
      #pragma unroll
      for (int h = 0; h < 2; ++h) {
        uint4 xv[8];
        #pragma unroll
        for (int j = 0; j < 8; ++j) xv[j] = xs[h * 8 + j];
        a1 = dot8<816>(wp + (0 * 16 + h * 8) * 816, xv, a1);
        a2 = dot8<816>(wp + (1 * 16 + h * 8) * 816, xv, a2);
        at = dot8<816>(wp + (2 * 16 + h * 8) * 816, xv, at);
      }
      pB[uB * 13 + sB_ * 3 + 0] = a1;
      pB[uB * 13 + sB_ * 3 + 1] = a2;
      pB[uB * 13 + sB_ * 3 + 2] = at;
    }
    __syncthreads();
  }

  // ---- epilogue ----
  if (tid < 204) {   // B-finish t=511 -> hc(511)
    int b = tid * 13;
    float a1 = pB[b+0] + pB[b+3] + pB[b+6] + pB[b+9];
    float a2 = pB[b+1] + pB[b+4] + pB[b+7] + pB[b+10];
    float at = pB[b+2] + pB[b+5] + pB[b+8] + pB[b+11];
    XB32[306 + tid] = cellact3(a1, a2, at, bb);
  }
  __syncthreads();
  if (tid >= 960) {  // hm(511) from hc(511) + hm(510)
    float a1 = 0.f, a2 = 0.f, at = 0.f;
    #pragma unroll
    for (int j = 0; j < 7; ++j) {
      int d = ch * 7 + j;
      float xv = (d < 204) ? XB32[306 + d] : (d == 204 ? hm0 : (d == 205 ? hm1 : 0.f));
      a1 = fmaf(wc1[j], xv, a1); a2 = fmaf(wc2[j], xv, a2); at = fmaf(wct[j], xv, at);
    }
    #pragma unroll
    for (int m = 2; m <= 32; m <<= 1) {
      a1 += __shfl_xor(a1, m); a2 += __shfl_xor(a2, m); at += __shfl_xor(at, m);
    }
    float hmn = cellact3(a1, a2, at, b2);
    if (l15 < 2) shm2[u2] = hmn;
  }
  __syncthreads();

  if (tid < 2) {
    int o = tid;
    out[(size_t)row * 2 + o] = shm2[0] * fcw[o * 2 + 0] + shm2[1] * fcw[o * 2 + 1] + fcb[o];
  }
  if (tid < 512) {
    float v = (tid < 510) ? XB32[tid] : shm2[tid - 510];
    out[512 + (size_t)row * 512 + tid] = v;
  }
}

extern "C" void kernel_launch(void* const* d_in, const int* in_sizes, int n_in,
                              void* d_out, int out_size, void* d_ws, size_t ws_size,
                              hipStream_t stream) {
  const float* x    = (const float*)d_in[0];
  const float* h0   = (const float*)d_in[1];
  const float* f1w0 = (const float*)d_in[2];
  const float* f1b0 = (const float*)d_in[3];
  const float* f2w0 = (const float*)d_in[4];
  const float* f2b0 = (const float*)d_in[5];
  const float* taw0 = (const float*)d_in[6];
  const float* tab0 = (const float*)d_in[7];
  const float* tbw0 = (const float*)d_in[8];
  const float* tbb0 = (const float*)d_in[9];
  const int*   m0   = (const int*)d_in[10];
  const float* f1w1 = (const float*)d_in[11];
  const float* f1b1 = (const float*)d_in[12];
  const float* f2w1 = (const float*)d_in[13];
  const float* f2b1 = (const float*)d_in[14];
  const float* taw1 = (const float*)d_in[15];
  const float* tab1 = (const float*)d_in[16];
  const float* tbw1 = (const float*)d_in[17];
  const float* tbb1 = (const float*)d_in[18];
  const int*   m1   = (const int*)d_in[19];
  const float* f1w2 = (const float*)d_in[20];
  const float* f1b2 = (const float*)d_in[21];
  const float* f2w2 = (const float*)d_in[22];
  const float* f2b2 = (const float*)d_in[23];
  const float* taw2 = (const float*)d_in[24];
  const float* tab2 = (const float*)d_in[25];
  const float* tbw2 = (const float*)d_in[26];
  const float* tbb2 = (const float*)d_in[27];
  const int*   m2   = (const int*)d_in[28];
  const float* fcw  = (const float*)d_in[29];
  const float* fcb  = (const float*)d_in[30];

  float* ws  = (float*)d_ws;
  float* out = (float*)d_out;

  // prep items: 176256 + 156672 + 416 + 306 + 204 + 2 = 333,856
  prep_kernel<<<1305, 256, 0, stream>>>(
      f1w0, f2w0, taw0, tbw0, m0, f1b0, f2b0, tab0, tbb0,
      f1w1, f2w1, taw1, tbw1, m1, f1b1, f2b1, tab1, tbb1,
      f1w2, f2w2, taw2, tbw2, m2, f1b2, f2b2, tab2, tbb2,
      ws);

  lnn_main<<<256, 1024, 0, stream>>>(x, h0, fcw, fcb, ws, out);
}